// Round 2
// baseline (680.634 us; speedup 1.0000x reference)
//
#include <hip/hip_runtime.h>

#define B_   16
#define L_   1536
#define D_   512
#define DFF_ 2048
#define NM   64
#define HID  256

typedef short short8  __attribute__((ext_vector_type(8)));
typedef short short4v __attribute__((ext_vector_type(4)));
typedef float f32x4   __attribute__((ext_vector_type(4)));

__device__ __forceinline__ float b2f(short s) {
  unsigned int u = ((unsigned int)(unsigned short)s) << 16;
  float f; __builtin_memcpy(&f, &u, 4); return f;
}
__device__ __forceinline__ short f2b(float f) {
  unsigned int u; __builtin_memcpy(&u, &f, 4);
  u += 0x7fffu + ((u >> 16) & 1u);
  return (short)(u >> 16);
}
__device__ __forceinline__ f32x4 zero4() {
  f32x4 v; v[0]=0.f; v[1]=0.f; v[2]=0.f; v[3]=0.f; return v;
}

#define MFMA(a,b,c) __builtin_amdgcn_mfma_f32_16x16x32_bf16((a),(b),(c),0,0,0)
// XOR-swizzled LDS offset for a 64-row x 64-col (8 groups of 8 shorts) tile.
#define SWZ(row, grp) (((row) << 6) + ((((grp) ^ ((row) & 7))) << 3))

// ---------------- guard: zero output (ws too small diagnostic) ----------------
__global__ __launch_bounds__(256) void zero_out(float* __restrict__ o, int n) {
  int i = blockIdx.x * 256 + threadIdx.x;
  if (i < n) o[i] = 0.f;
}

// ---------------- fp32 -> bf16 convert ----------------
__global__ __launch_bounds__(256) void cvt_f32_bf16(const float* __restrict__ s,
                                                    short* __restrict__ d, int n4) {
  int i = blockIdx.x * 256 + threadIdx.x;
  if (i >= n4) return;
  f32x4 v = ((const f32x4*)s)[i];
  short4v o;
  #pragma unroll
  for (int j = 0; j < 4; ++j) o[j] = f2b(v[j]);
  ((short4v*)d)[i] = o;
}

// ---------------- DFT tables ----------------
__global__ __launch_bounds__(256) void build_fwd_tables(short* __restrict__ tc,
                                                        short* __restrict__ ts) {
  int i = blockIdx.x * 256 + threadIdx.x;
  if (i >= NM * L_) return;
  int m = i / L_, l = i - m * L_;
  int r = (m * l) % L_;                       // exact integer angle reduction
  float th = (float)r * (6.283185307179586f / (float)L_);
  float s, c; __sincosf(th, &s, &c);
  tc[i] = f2b(c);
  ts[i] = f2b(-s);
}
// basis[l][k]: k<64 -> ((k==0?1:2)/L)*cos(2pi k l/L); k>=64 -> (-2/L)*sin(2pi (k-64) l/L)
__global__ __launch_bounds__(256) void build_basis(short* __restrict__ basis) {
  int i = blockIdx.x * 256 + threadIdx.x;
  if (i >= L_ * 128) return;
  int l = i >> 7, k = i & 127;
  int m = (k < 64) ? k : (k - 64);
  int r = (m * l) % L_;
  float th = (float)r * (6.283185307179586f / (float)L_);
  float s, c; __sincosf(th, &s, &c);
  float v = (k < 64) ? ((m == 0) ? 1.f : 2.f) * (1.f / (float)L_) * c
                     : (-2.f / (float)L_) * s;
  basis[i] = f2b(v);
}

// ---------------- w[d][e][m] f32 -> wt[mLocal][e][d] bf16, 16-mode chunk ----------------
__global__ __launch_bounds__(256) void transpose_w16(const float* __restrict__ w,
                                                     short* __restrict__ wt, int mBase) {
  __shared__ float tile[64][17];
  int dc = blockIdx.x, e = blockIdx.y, t = threadIdx.x;
  {
    int dl = t >> 2, mg = t & 3;
    f32x4 v = *(const f32x4*)(w + ((long)(dc * 64 + dl) * 512 + e) * 64 + mBase + mg * 4);
    tile[dl][mg*4+0] = v[0]; tile[dl][mg*4+1] = v[1];
    tile[dl][mg*4+2] = v[2]; tile[dl][mg*4+3] = v[3];
  }
  __syncthreads();
  if (t < 128) {
    int mr = t >> 3, dg = t & 7;
    short8 o;
    #pragma unroll
    for (int j = 0; j < 8; ++j) o[j] = f2b(tile[dg * 8 + j][mr]);
    *(short8*)(wt + ((long)mr * 512 + e) * 512 + dc * 64 + dg * 8) = o;
  }
}

// ---------------- x[b][l][d] f32 -> xt[b][d][l] bf16 ----------------
__global__ __launch_bounds__(256) void transpose_x(const float* __restrict__ x,
                                                   short* __restrict__ xt) {
  __shared__ float tile[64][65];
  int dc = blockIdx.x, lc = blockIdx.y, b = blockIdx.z, t = threadIdx.x;
  const float* xb = x + (long)b * L_ * D_;
  #pragma unroll
  for (int i = 0; i < 4; ++i) {
    int idx = i * 256 + t; int ll = idx >> 4, dg = idx & 15;
    f32x4 v = *(const f32x4*)(xb + (long)(lc * 64 + ll) * D_ + dc * 64 + dg * 4);
    tile[ll][dg*4+0] = v[0]; tile[ll][dg*4+1] = v[1];
    tile[ll][dg*4+2] = v[2]; tile[ll][dg*4+3] = v[3];
  }
  __syncthreads();
  #pragma unroll
  for (int i = 0; i < 2; ++i) {
    int idx = i * 256 + t; int dl = idx >> 3, lg = idx & 7;
    short8 o;
    #pragma unroll
    for (int j = 0; j < 8; ++j) o[j] = f2b(tile[lg * 8 + j][dl]);
    *(short8*)(xt + ((long)b * D_ + dc * 64 + dl) * L_ + lc * 64 + lg * 8) = o;
  }
}

// ---------------- generic 64x64-tile bf16 MFMA GEMM: C = act(A * W^T + bias) + res ----------------
// A: (M,K) bf16 row-major (ldA, batch Az). W: (N,K) bf16 row-major (ldW, batch Wz).
// out addr = z*csz + row*csr + col*csc. res addr = z*resZ + row*ldres + col (fp32 or bf16 per RESB).
template<bool RELU, bool HASBIAS, bool HASRES, bool RESB, bool OUTB>
__global__ __launch_bounds__(256) void gemm64(
    const short* __restrict__ A, long ldA, long Az,
    const short* __restrict__ W, long ldW, long Wz,
    const float* __restrict__ bias,
    const void* __restrict__ res, long ldres, long resZ,
    short* __restrict__ outB,
    long csr, long csc, long csz, int K)
{
  __shared__ short lA[64 * 64];
  __shared__ short lW[64 * 64];
  const int t = threadIdx.x;
  const int lane = t & 63, wid = t >> 6;
  const int quad = lane >> 4, l15 = lane & 15;
  const int wm = (wid & 1) * 32, wn = (wid >> 1) * 32;
  const long row0 = (long)blockIdx.x * 64;
  const long col0 = (long)blockIdx.y * 64;
  const int z = blockIdx.z;
  const short* Ab = A + (long)z * Az + row0 * ldA;
  const short* Wb = W + (long)z * Wz + col0 * ldW;

  f32x4 acc[2][2];
  #pragma unroll
  for (int i = 0; i < 2; ++i)
    #pragma unroll
    for (int j = 0; j < 2; ++j) acc[i][j] = zero4();

  for (int k0 = 0; k0 < K; k0 += 64) {
    __syncthreads();
    #pragma unroll
    for (int i = 0; i < 2; ++i) {
      int idx = i * 256 + t;
      int r = idx >> 3, cg = idx & 7;
      *(short8*)&lA[SWZ(r, cg)] = *(const short8*)(Ab + (long)r * ldA + k0 + cg * 8);
      *(short8*)&lW[SWZ(r, cg)] = *(const short8*)(Wb + (long)r * ldW + k0 + cg * 8);
    }
    __syncthreads();
    #pragma unroll
    for (int ks = 0; ks < 2; ++ks) {
      int gq = ks * 4 + quad;
      short8 a0 = *(const short8*)&lA[SWZ(wm + l15, gq)];
      short8 a1 = *(const short8*)&lA[SWZ(wm + 16 + l15, gq)];
      short8 b0 = *(const short8*)&lW[SWZ(wn + l15, gq)];
      short8 b1 = *(const short8*)&lW[SWZ(wn + 16 + l15, gq)];
      acc[0][0] = MFMA(a0, b0, acc[0][0]);
      acc[0][1] = MFMA(a0, b1, acc[0][1]);
      acc[1][0] = MFMA(a1, b0, acc[1][0]);
      acc[1][1] = MFMA(a1, b1, acc[1][1]);
    }
  }
  // C/D layout: col=lane&15, row=quad*4+reg (verified m89/m91)
  #pragma unroll
  for (int ni = 0; ni < 2; ++ni) {
    long col = col0 + wn + ni * 16 + l15;
    float bv = HASBIAS ? bias[col] : 0.f;
    #pragma unroll
    for (int mi = 0; mi < 2; ++mi) {
      #pragma unroll
      for (int r = 0; r < 4; ++r) {
        long row = row0 + wm + mi * 16 + quad * 4 + r;
        float v = acc[mi][ni][r];
        if (HASBIAS) v += bv;
        if (RELU)    v = fmaxf(v, 0.f);
        if (HASRES) {
          long ro = (long)z * resZ + row * ldres + col;
          v += RESB ? b2f(((const short*)res)[ro]) : ((const float*)res)[ro];
        }
        outB[(long)z * csz + row * csr + col * csc] = f2b(v);
      }
    }
  }
}

// ---------------- per-mode complex GEMM (16-mode chunk) ----------------
// qr/qi: [m][b][d] bf16 (global mode index); wr/wi: [mLocal][e][d] bf16 chunk;
// outm: (b,e,128) bf16 [0:64 real | 64:128 imag]
__global__ __launch_bounds__(256) void mode_gemm(
    const short* __restrict__ qr, const short* __restrict__ qi,
    const short* __restrict__ wr, const short* __restrict__ wi,
    short* __restrict__ outm, int mBase)
{
  __shared__ short lqr[16 * 64], lqi[16 * 64], lwr[64 * 64], lwi[64 * 64];
  const int ml = blockIdx.x, en = blockIdx.y;
  const int m = mBase + ml;
  const int t = threadIdx.x, lane = t & 63, wid = t >> 6;
  const int quad = lane >> 4, l15 = lane & 15;
  const short* qrb = qr + (long)m * (B_ * D_);
  const short* qib = qi + (long)m * (B_ * D_);
  const short* wrb = wr + (long)ml * (D_ * D_) + (long)en * 64 * D_;
  const short* wib = wi + (long)ml * (D_ * D_) + (long)en * 64 * D_;
  f32x4 accr = zero4(), acci = zero4();
  for (int k0 = 0; k0 < D_; k0 += 64) {
    __syncthreads();
    {
      int idx = t & 127; int r = idx >> 3, cg = idx & 7;
      const short* src = (t < 128 ? qrb : qib) + r * D_ + k0 + cg * 8;
      short* dst = (t < 128) ? lqr : lqi;
      *(short8*)&dst[SWZ(r, cg)] = *(const short8*)src;
    }
    #pragma unroll
    for (int i = 0; i < 4; ++i) {
      int idx = i * 256 + t;
      int which = idx >> 9, idx2 = idx & 511;
      int r = idx2 >> 3, cg = idx2 & 7;
      const short* src = (which ? wib : wrb) + r * D_ + k0 + cg * 8;
      short* dst = which ? lwi : lwr;
      *(short8*)&dst[SWZ(r, cg)] = *(const short8*)src;
    }
    __syncthreads();
    #pragma unroll
    for (int ks = 0; ks < 2; ++ks) {
      int gq = ks * 4 + quad;
      short8 ar = *(const short8*)&lqr[SWZ(l15, gq)];
      short8 ai = *(const short8*)&lqi[SWZ(l15, gq)];
      short8 br = *(const short8*)&lwr[SWZ(wid * 16 + l15, gq)];
      short8 bi = *(const short8*)&lwi[SWZ(wid * 16 + l15, gq)];
      short8 nai;
      #pragma unroll
      for (int j = 0; j < 8; ++j) nai[j] = (short)(ai[j] ^ (short)0x8000);
      accr = MFMA(ar, br, accr);
      accr = MFMA(nai, bi, accr);   // - qi*wi
      acci = MFMA(ar, bi, acci);
      acci = MFMA(ai, br, acci);
    }
  }
  #pragma unroll
  for (int r = 0; r < 4; ++r) {
    int bb = quad * 4 + r;                       // row = b (M=16 exact)
    long e = (long)en * 64 + wid * 16 + l15;     // col = e
    long base = ((long)bb * D_ + e) * 128 + m;
    outm[base]      = f2b(accr[r]);
    outm[base + 64] = f2b(acci[r]);
  }
}

// ---------------- 3-expert gates: softmax(h @ w2^T + b2) ----------------
__global__ __launch_bounds__(256) void gates_kernel(
    const short* __restrict__ h, const float* __restrict__ w2,
    const float* __restrict__ b2, float* __restrict__ g, int rows)
{
  int wid = threadIdx.x >> 6, lane = threadIdx.x & 63;
  int row = blockIdx.x * 4 + wid;
  if (row >= rows) return;
  const short* hr = h + (long)row * HID;
  short4v hh = *(const short4v*)(hr + lane * 4);
  float hv[4];
  #pragma unroll
  for (int j = 0; j < 4; ++j) hv[j] = b2f(hh[j]);
  float lg[3];
  #pragma unroll
  for (int e = 0; e < 3; ++e) {
    const float* wrow = w2 + e * HID + lane * 4;
    float p = hv[0] * wrow[0] + hv[1] * wrow[1] + hv[2] * wrow[2] + hv[3] * wrow[3];
    #pragma unroll
    for (int off = 32; off >= 1; off >>= 1) p += __shfl_xor(p, off);
    lg[e] = p + b2[e];
  }
  float mx = fmaxf(lg[0], fmaxf(lg[1], lg[2]));
  float e0 = __expf(lg[0] - mx), e1 = __expf(lg[1] - mx), e2 = __expf(lg[2] - mx);
  float inv = 1.f / (e0 + e1 + e2);
  float gv = (lane == 0) ? e0 * inv : (lane == 1) ? e1 * inv : e2 * inv;
  if (lane < 3) g[(long)row * 3 + lane] = gv;
}

// ---------------- seasonal combine: out = x - sum_e gate_e * avgpool_{3,5,7}(x) ----------------
template<bool OUTF, bool WRITEB>
__global__ __launch_bounds__(512) void combine_kernel(
    const short* __restrict__ xin, const float* __restrict__ g,
    float* __restrict__ outf, short* __restrict__ outb)
{
  int lc = blockIdx.x, b = blockIdx.y, d = threadIdx.x;
  int l0 = lc * 64;
  const short* xb = xin + (long)b * L_ * D_ + d;
  const float* gb = g + (long)b * L_ * 3;
  float win[7];
  #pragma unroll
  for (int j = 0; j < 6; ++j) {
    int l = l0 - 3 + j;
    win[j] = (l >= 0 && l < L_) ? b2f(xb[(long)l * D_]) : 0.f;
  }
  for (int i = 0; i < 64; ++i) {
    int lcn = l0 + i;
    int lr = lcn + 3;
    win[6] = (lr < L_) ? b2f(xb[(long)lr * D_]) : 0.f;
    float s3 = win[2] + win[3] + win[4];
    float s5 = s3 + win[1] + win[5];
    float s7 = s5 + win[0] + win[6];
    float g0 = gb[lcn * 3 + 0], g1 = gb[lcn * 3 + 1], g2 = gb[lcn * 3 + 2];
    float trend = g0 * s3 * (1.f / 3.f) + g1 * s5 * (1.f / 5.f) + g2 * s7 * (1.f / 7.f);
    float v = win[3] - trend;
    long o = ((long)b * L_ + lcn) * D_ + d;
    if (OUTF)   outf[o] = v;
    if (WRITEB) outb[o] = f2b(v);
    #pragma unroll
    for (int j = 0; j < 6; ++j) win[j] = win[j + 1];
  }
}

extern "C" void kernel_launch(void* const* d_in, const int* in_sizes, int n_in,
                              void* d_out, int out_size, void* d_ws, size_t ws_size,
                              hipStream_t stream) {
  const float* x       = (const float*)d_in[0];
  const float* w_real  = (const float*)d_in[1];
  const float* w_imag  = (const float*)d_in[2];
  const float* conv1_w = (const float*)d_in[3];
  const float* conv2_w = (const float*)d_in[4];
  const float* d1_w1   = (const float*)d_in[5];
  const float* d1_b1   = (const float*)d_in[6];
  const float* d1_w2   = (const float*)d_in[7];
  const float* d1_b2   = (const float*)d_in[8];
  const float* d2_w1   = (const float*)d_in[9];
  const float* d2_b1   = (const float*)d_in[10];
  const float* d2_w2   = (const float*)d_in[11];
  const float* d2_b2   = (const float*)d_in[12];
  float* OUT = (float*)d_out;

  // ---- workspace guard: peak arena = 115,343,360 B (~110 MB) ----
  const size_t REQUIRED = 115343360;
  if (ws_size < REQUIRED) {   // diagnostic path: clean absmax-fail instead of segfault
    zero_out<<<(out_size + 255) / 256, 256, 0, stream>>>(OUT, out_size);
    return;
  }

  char* ws = (char*)d_ws;
  // Arena (all offsets 64KB-aligned). Lifetime aliasing:
  //   XT dies after fwd DFT -> Y1C (FFN1 chunk out) reuses it.
  //   X1B dies after combine1 -> ZB (FFN2 out) reuses it.
  short* C1WB  = (short*)(ws + 0);          //  2,097,152
  short* C2WB  = (short*)(ws + 2097152);    //  2,097,152
  short* D1W1B = (short*)(ws + 4194304);    //    262,144
  short* D2W1B = (short*)(ws + 4456448);    //    262,144
  short* TC    = (short*)(ws + 4718592);    //    196,608
  short* TS    = (short*)(ws + 4915200);    //    196,608
  short* BASIS = (short*)(ws + 5111808);    //    393,216
  float* G     = (float*)(ws + 5505024);    //    294,912
  short* XT    = (short*)(ws + 6291456);    // 25,165,824  (aliased by Y1C)
  short* Y1C   = XT;
  short* QR    = (short*)(ws + 31457280);   //  1,048,576
  short* QI    = (short*)(ws + 32505856);   //  1,048,576
  short* OUTM  = (short*)(ws + 33554432);   //  2,097,152
  short* WCR   = (short*)(ws + 35651584);   //  8,388,608  (16-mode chunk)
  short* WCI   = (short*)(ws + 44040192);   //  8,388,608
  short* X1B   = (short*)(ws + 52428800);   // 25,165,824  (aliased by ZB)
  short* ZB    = X1B;
  short* X2B   = (short*)(ws + 77594624);   // 25,165,824
  short* H     = (short*)(ws + 102760448);  // 12,582,912  -> end 115,343,360

  // --- weight prep ---
  cvt_f32_bf16<<<(262144 + 255) / 256, 256, 0, stream>>>(conv1_w, C1WB, 262144);
  cvt_f32_bf16<<<(262144 + 255) / 256, 256, 0, stream>>>(conv2_w, C2WB, 262144);
  cvt_f32_bf16<<<(32768 + 255) / 256, 256, 0, stream>>>(d1_w1, D1W1B, 32768);
  cvt_f32_bf16<<<(32768 + 255) / 256, 256, 0, stream>>>(d2_w1, D2W1B, 32768);
  build_fwd_tables<<<(NM * L_ + 255) / 256, 256, 0, stream>>>(TC, TS);
  build_basis<<<(L_ * 128 + 255) / 256, 256, 0, stream>>>(BASIS);
  transpose_x<<<dim3(8, 24, 16), 256, 0, stream>>>(x, XT);

  // --- forward DFT (64 modes): QR/QI[m][b][d] = sum_l xt[b][d][l] * table[m][l] ---
  // out addr = col*8192 (m) + z*512 (b) + row (d): csr=1, csc=B*D, csz=D.
  gemm64<false, false, false, false, true><<<dim3(8, 1, 16), 256, 0, stream>>>(
      XT, L_, (long)D_ * L_, TC, L_, 0, nullptr, nullptr, 0, 0,
      QR, 1, (long)B_ * D_, D_, L_);
  gemm64<false, false, false, false, true><<<dim3(8, 1, 16), 256, 0, stream>>>(
      XT, L_, (long)D_ * L_, TS, L_, 0, nullptr, nullptr, 0, 0,
      QI, 1, (long)B_ * D_, D_, L_);

  // --- per-mode complex matmul, 4 chunks of 16 modes ---
  for (int c = 0; c < 4; ++c) {
    transpose_w16<<<dim3(8, 512), 256, 0, stream>>>(w_real, WCR, c * 16);
    transpose_w16<<<dim3(8, 512), 256, 0, stream>>>(w_imag, WCI, c * 16);
    mode_gemm<<<dim3(16, 8), 256, 0, stream>>>(QR, QI, WCR, WCI, OUTM, c * 16);
  }

  // --- inverse DFT + residual: x1 = x + irfft  (bf16 out) ---
  gemm64<false, false, true, false, true><<<dim3(24, 8, 16), 256, 0, stream>>>(
      BASIS, 128, 0, OUTM, 128, (long)D_ * 128, nullptr,
      x, D_, (long)L_ * D_, X1B, D_, 1, (long)L_ * D_, 128);

  // --- decomp 1 ---
  gemm64<true, true, false, false, true><<<dim3(384, 4, 1), 256, 0, stream>>>(
      X1B, D_, 0, D1W1B, D_, 0, d1_b1, nullptr, 0, 0,
      H, HID, 1, 0, D_);
  gates_kernel<<<6144, 256, 0, stream>>>(H, d1_w2, d1_b2, G, B_ * L_);
  combine_kernel<false, true><<<dim3(24, 16), 512, 0, stream>>>(X1B, G, nullptr, X2B);

  // --- FFN, 4 row-chunks of 6144 (Y1 chunk aliases dead XT; ZB aliases dead X1B) ---
  for (int rc = 0; rc < 4; ++rc) {
    const short* Ain = X2B + (long)rc * 6144 * D_;
    gemm64<true, false, false, false, true><<<dim3(96, 32, 1), 256, 0, stream>>>(
        Ain, D_, 0, C1WB, D_, 0, nullptr, nullptr, 0, 0,
        Y1C, DFF_, 1, 0, D_);
    gemm64<false, false, true, true, true><<<dim3(96, 8, 1), 256, 0, stream>>>(
        Y1C, DFF_, 0, C2WB, DFF_, 0, nullptr, Ain, D_, 0,
        ZB + (long)rc * 6144 * D_, D_, 1, 0, DFF_);
  }

  // --- decomp 2 -> d_out ---
  gemm64<true, true, false, false, true><<<dim3(384, 4, 1), 256, 0, stream>>>(
      ZB, D_, 0, D2W1B, D_, 0, d2_b1, nullptr, 0, 0,
      H, HID, 1, 0, D_);
  gates_kernel<<<6144, 256, 0, stream>>>(H, d2_w2, d2_b2, G, B_ * L_);
  combine_kernel<true, false><<<dim3(24, 16), 512, 0, stream>>>(ZB, G, OUT, nullptr);
}